// Round 2
// baseline (567.947 us; speedup 1.0000x reference)
//
#include <hip/hip_runtime.h>
#include <stdint.h>

// StochLinear: out[b,n] = 2048 - 0.25 * popcount(A_bits[b] ^ W_bits[n]) + bias[n]
// where A_bits / W_bits are JAX threefry2x32 (partitionable mode) Bernoulli bits.
// B=4096, K=2048, N=2048, L=8 -> 256 u64 words per packed row.

#define B_DIM 4096
#define K_DIM 2048
#define N_DIM 2048
#define WORDS 256  // L*K/64

__host__ __device__ static inline void tf2x32(uint32_t ks0, uint32_t ks1,
                                              uint32_t x0, uint32_t x1,
                                              uint32_t* o0, uint32_t* o1) {
  uint32_t ks2 = ks0 ^ ks1 ^ 0x1BD11BDAu;
  x0 += ks0; x1 += ks1;
#define TF_RND(r) { x0 += x1; x1 = (x1 << (r)) | (x1 >> (32 - (r))); x1 ^= x0; }
  TF_RND(13) TF_RND(15) TF_RND(26) TF_RND(6)
  x0 += ks1; x1 += ks2 + 1u;
  TF_RND(17) TF_RND(29) TF_RND(16) TF_RND(24)
  x0 += ks2; x1 += ks0 + 2u;
  TF_RND(13) TF_RND(15) TF_RND(26) TF_RND(6)
  x0 += ks0; x1 += ks1 + 3u;
  TF_RND(17) TF_RND(29) TF_RND(16) TF_RND(24)
  x0 += ks1; x1 += ks2 + 4u;
  TF_RND(13) TF_RND(15) TF_RND(26) TF_RND(6)
  x0 += ks2; x1 += ks0 + 5u;
  *o0 = x0; *o1 = x1;
#undef TF_RND
}

// One threefry block per lane; __ballot packs 64 bits -> one u64 word per wave.
// A element (l,b,k): linear idx = (l*4096+b)*2048+k. Packed: Ap[b][l*32+kw].
__global__ __launch_bounds__(256) void stoch_bits_x(const float* __restrict__ x,
                                                    unsigned long long* __restrict__ Ap,
                                                    uint32_t k0, uint32_t k1) {
  unsigned gw = (unsigned)blockIdx.x * 4u + (threadIdx.x >> 6);
  unsigned lane = threadIdx.x & 63u;
  unsigned kw = gw & 31u;          // u64 word within row-slice (k/64)
  unsigned b  = (gw >> 5) & 4095u;
  unsigned l  = gw >> 17;          // 0..7
  unsigned k  = (kw << 6) + lane;
  uint32_t idx = ((l << 12) + b) * 2048u + k;  // < 2^26, hi32 = 0
  uint32_t o0, o1;
  tf2x32(k0, k1, 0u, idx, &o0, &o1);
  uint32_t bits = o0 ^ o1;
  float u = __uint_as_float((bits >> 9) | 0x3F800000u) - 1.0f;
  float v = x[(size_t)b * 2048u + k];
  float p = fminf(fmaxf((v + 1.0f) * 0.5f, 0.0f), 1.0f);
  unsigned long long m = __ballot(u < p);
  if (lane == 0) Ap[(size_t)b * WORDS + (l << 5) + kw] = m;
}

// W element (l,k,n) of weight.T: linear idx = l*K*N + k*N + n; value = weight[n][k].
// Packed along k: Wp[n][l*32+kw].
__global__ __launch_bounds__(256) void stoch_bits_w(const float* __restrict__ wgt,
                                                    unsigned long long* __restrict__ Wp,
                                                    uint32_t k0, uint32_t k1) {
  unsigned gw = (unsigned)blockIdx.x * 4u + (threadIdx.x >> 6);
  unsigned lane = threadIdx.x & 63u;
  unsigned kw = gw & 31u;
  unsigned n  = (gw >> 5) & 2047u;
  unsigned l  = gw >> 16;          // 0..7
  unsigned k  = (kw << 6) + lane;
  uint32_t idx = ((l << 11) + k) * 2048u + n;  // < 2^25, hi32 = 0
  uint32_t o0, o1;
  tf2x32(k0, k1, 0u, idx, &o0, &o1);
  uint32_t bits = o0 ^ o1;
  float u = __uint_as_float((bits >> 9) | 0x3F800000u) - 1.0f;
  float v = wgt[(size_t)n * 2048u + k];
  float p = fminf(fmaxf((v + 1.0f) * 0.5f, 0.0f), 1.0f);
  unsigned long long m = __ballot(u < p);
  if (lane == 0) Wp[(size_t)n * WORDS + (l << 5) + kw] = m;
}

// XOR-popcount GEMM: 64x64 output tile per block, 4x4 per thread, w-chunks of 32 u64.
__global__ __launch_bounds__(256) void xnor_gemm(const unsigned long long* __restrict__ Ap,
                                                 const unsigned long long* __restrict__ Wp,
                                                 const float* __restrict__ bias,
                                                 float* __restrict__ out) {
  __shared__ unsigned long long As[64][33];  // pad -> conflict-free strided reads
  __shared__ unsigned long long Ws[64][33];
  const int tid = threadIdx.x;
  const int brow = blockIdx.y << 6;
  const int bcol = blockIdx.x << 6;
  const int tx = tid & 15, ty = tid >> 4;
  uint32_t cnt[4][4] = {};
#pragma unroll 1
  for (int c = 0; c < 8; ++c) {
    if (c) __syncthreads();
#pragma unroll
    for (int i = 0; i < 8; ++i) {
      int idx = tid + (i << 8);
      int r = idx >> 5, w = idx & 31;
      As[r][w] = Ap[(size_t)(brow + r) * WORDS + (c << 5) + w];
      Ws[r][w] = Wp[(size_t)(bcol + r) * WORDS + (c << 5) + w];
    }
    __syncthreads();
#pragma unroll 8
    for (int w = 0; w < 32; ++w) {
      unsigned long long av[4], bv[4];
#pragma unroll
      for (int i = 0; i < 4; ++i) av[i] = As[(ty << 2) + i][w];
#pragma unroll
      for (int j = 0; j < 4; ++j) bv[j] = Ws[(tx << 2) + j][w];
#pragma unroll
      for (int i = 0; i < 4; ++i)
#pragma unroll
        for (int j = 0; j < 4; ++j)
          cnt[i][j] += (uint32_t)__popcll(av[i] ^ bv[j]);
    }
  }
#pragma unroll
  for (int i = 0; i < 4; ++i) {
    int r = brow + (ty << 2) + i;
#pragma unroll
    for (int j = 0; j < 4; ++j) {
      int n = bcol + (tx << 2) + j;
      out[(size_t)r * N_DIM + n] = 2048.0f - 0.25f * (float)cnt[i][j] + bias[n];
    }
  }
}

extern "C" void kernel_launch(void* const* d_in, const int* in_sizes, int n_in,
                              void* d_out, int out_size, void* d_ws, size_t ws_size,
                              hipStream_t stream) {
  const float* x = (const float*)d_in[0];
  const float* wgt = (const float*)d_in[1];
  const float* bias = (const float*)d_in[2];
  float* out = (float*)d_out;

  unsigned long long* Ap = (unsigned long long*)d_ws;           // 4096*256*8 = 8 MB
  unsigned long long* Wp = Ap + (size_t)B_DIM * WORDS;          // 2048*256*8 = 4 MB

  // key(42) = (0,42); partitionable (fold-like) split:
  //   kA = threefry((0,42),(0,0)), kB = threefry((0,42),(0,1))
  uint32_t kA0, kA1, kB0, kB1;
  tf2x32(0u, 42u, 0u, 0u, &kA0, &kA1);
  tf2x32(0u, 42u, 0u, 1u, &kB0, &kB1);

  // A bits: 8*4096*32 waves = 2^20 -> 262144 blocks of 4 waves
  stoch_bits_x<<<262144, 256, 0, stream>>>(x, Ap, kA0, kA1);
  // W bits: 8*2048*32 waves = 2^19 -> 131072 blocks
  stoch_bits_w<<<131072, 256, 0, stream>>>(wgt, Wp, kB0, kB1);
  // GEMM: (2048/64) x (4096/64)
  dim3 grid(N_DIM / 64, B_DIM / 64);
  xnor_gemm<<<grid, 256, 0, stream>>>(Ap, Wp, bias, out);
  (void)in_sizes; (void)n_in; (void)out_size; (void)ws_size;
}